// Round 10
// baseline (127.385 us; speedup 1.0000x reference)
//
#include <hip/hip_runtime.h>
#include <math.h>

// Problem constants (fixed by the reference): x,y are [4, 64, 64, 64] fp32.
constexpr int B_   = 4;
constexpr int C_   = 64;
constexpr int HW   = 4096;         // N = 64*64
constexpr int ROWS = B_ * HW;      // 16384

constexpr float SIGMA    = 0.1f;
constexpr float EPS_MIN  = 1e-5f;
constexpr float EPS_NORM = 1e-12f;
constexpr float LOG2E    = 1.44269504088896340736f;

// Fused-kernel geometry: block owns XR=32 x-rows x ALL 4096 y (dmin
// block-local). 8 waves (512 thr) split y 8-ways. NO LDS staging: each
// lane's MFMA A-fragment is loaded directly from L2-resident y with
// 2-tile-deep register prefetch (R8 post-mortem: LDS pipe ~20us/CU was
// the largest consumer; direct loads have identical per-lane values).
constexpr int XR = 32;             // x-rows per block (2 MFMA col-tiles)
constexpr int NW = 8;              // waves per block
constexpr int YW = HW / NW;        // 512 y-rows per wave
constexpr int NT = YW / 16;        // 32 y-tiles (16 rows) per wave per sweep

using short8  = __attribute__((ext_vector_type(8))) short;   // 8 bf16
using floatx4 = __attribute__((ext_vector_type(4))) float;

struct Frag { short8 a0, a1; };    // one 16-row y-tile: k 0..31 / 32..63

__device__ inline ushort f2bf(float f) {           // RNE float->bf16
    unsigned u = __float_as_uint(f);
    unsigned r = u + 0x7FFFu + ((u >> 16) & 1u);
    return (ushort)(r >> 16);
}

// ---------------------------------------------------------------------------
// Normalize along C, write bf16 [B][N][C] point-major.
// TRICK: xn is pre-scaled by -2 (exact in bf16) so the MFMA with C-init=2
// produces d^2 = 2 - 2*dot directly.  yn is the plain unit vector.
__global__ __launch_bounds__(256) void nrm_kernel(const float* __restrict__ x,
                                                  const float* __restrict__ y,
                                                  ushort* __restrict__ xn,
                                                  ushort* __restrict__ yn,
                                                  float* __restrict__ total) {
    int p = blockIdx.x * 256 + threadIdx.x;        // 0 .. 2*ROWS-1
    if (p == 0) *total = 0.0f;
    const float* src; ushort* dst; int q; float sgn;
    if (p < ROWS) { src = x; dst = xn; q = p; sgn = -2.0f; }
    else          { src = y; dst = yn; q = p - ROWS; sgn = 1.0f; }
    int b = q >> 12;
    int n = q & (HW - 1);
    const float* base = src + ((size_t)b * C_) * HW + n;  // coalesced over n
    float v[C_];
    float ss = 0.0f;
#pragma unroll
    for (int c = 0; c < C_; ++c) {
        v[c] = base[(size_t)c * HW];
        ss = fmaf(v[c], v[c], ss);
    }
    float scale = sgn / fmaxf(sqrtf(ss), EPS_NORM);
    short8* o = (short8*)(dst + (size_t)q * C_);
#pragma unroll
    for (int c8 = 0; c8 < C_ / 8; ++c8) {
        short8 pk;
#pragma unroll
        for (int j = 0; j < 8; ++j) pk[j] = (short)f2bf(v[c8 * 8 + j] * scale);
        o[c8] = pk;
    }
}

// ---------------------------------------------------------------------------
// Fused kernel. Swapped-operand MFMA (A=y, B=-2x, C=2): D = d^2 directly;
// D col = x point (lane&15), D row = y point.  Per-x-row reduction over y
// is in-register; cross-kgrp combine is 2 shfls per sweep.
// Sweep 1: min d^2 -> dmin (block-local LDS reduce across 8 waves).
// Sweep 2: S_row = sum_m exp2((dmin-d)*kk2), kk2 = log2e/(sigma*(dmin+eps));
//          then one atomicAdd per block of sum_rows(1/S + eps).
__global__ __launch_bounds__(512, 4) void main_kernel(const ushort* __restrict__ xn,
                                                      const ushort* __restrict__ yn,
                                                      float* __restrict__ total) {
    __shared__ float red[NW][XR];
    __shared__ float dmf[XR];

    const int tid  = threadIdx.x;
    const int wid  = tid >> 6;                     // 0..7
    const int lane = tid & 63;
    const int lrow = lane & 15;                    // A-row / x-col selector
    const int kgrp = lane >> 4;                    // k-group 0..3

    const int blk   = blockIdx.x;
    const int b     = blk >> 7;                    // 128 blocks per batch
    const int nbase = (blk & 127) * XR;

    // x B-fragments (pre-scaled by -2): 2 tiles x (k 0..31, k 32..63).
    const ushort* xb = xn + (size_t)(b * HW + nbase) * C_;
    short8 xf0[2], xf1[2];
#pragma unroll
    for (int xt = 0; xt < 2; ++xt) {
        xf0[xt] = *(const short8*)(xb + (xt * 16 + lrow) * C_ + kgrp * 8);
        xf1[xt] = *(const short8*)(xb + (xt * 16 + lrow) * C_ + 32 + kgrp * 8);
    }

    // This wave's y-eighth; per-lane A-frag base (row lrow, k-chunk kgrp).
    const ushort* lb = yn + (size_t)(b * HW + wid * YW + lrow) * C_ + kgrp * 8;

#define LDT(t) Frag{ *(const short8*)(lb + (t) * 16 * C_), \
                     *(const short8*)(lb + (t) * 16 * C_ + 32) }

    // ---------------- sweep 1: min d^2 ----------------
    float m2[2] = {INFINITY, INFINITY};
    {
        Frag fa = LDT(0), fb = LDT(1);
        for (int t = 0; t < NT; t += 2) {
            Frag fc = {}, fd = {};
            if (t + 2 < NT) fc = LDT(t + 2);
            if (t + 3 < NT) fd = LDT(t + 3);
#pragma unroll
            for (int xt = 0; xt < 2; ++xt) {
                floatx4 acc = {2.0f, 2.0f, 2.0f, 2.0f};
                acc = __builtin_amdgcn_mfma_f32_16x16x32_bf16(fa.a0, xf0[xt], acc, 0, 0, 0);
                acc = __builtin_amdgcn_mfma_f32_16x16x32_bf16(fa.a1, xf1[xt], acc, 0, 0, 0);
                m2[xt] = fminf(m2[xt],
                         fminf(fminf(acc[0], acc[1]), fminf(acc[2], acc[3])));
            }
#pragma unroll
            for (int xt = 0; xt < 2; ++xt) {
                floatx4 acc = {2.0f, 2.0f, 2.0f, 2.0f};
                acc = __builtin_amdgcn_mfma_f32_16x16x32_bf16(fb.a0, xf0[xt], acc, 0, 0, 0);
                acc = __builtin_amdgcn_mfma_f32_16x16x32_bf16(fb.a1, xf1[xt], acc, 0, 0, 0);
                m2[xt] = fminf(m2[xt],
                         fminf(fminf(acc[0], acc[1]), fminf(acc[2], acc[3])));
            }
            fa = fc; fb = fd;
        }
    }

    // Combine the 4 k-groups, then the 8 waves (disjoint y-subsets).
#pragma unroll
    for (int off = 16; off < 64; off <<= 1) {
        m2[0] = fminf(m2[0], __shfl_xor(m2[0], off));
        m2[1] = fminf(m2[1], __shfl_xor(m2[1], off));
    }
    if (kgrp == 0) { red[wid][lrow] = m2[0]; red[wid][16 + lrow] = m2[1]; }
    __syncthreads();
    if (tid < XR) {
        float m = red[0][tid];
#pragma unroll
        for (int w = 1; w < NW; ++w) m = fminf(m, red[w][tid]);
        dmf[tid] = sqrtf(fmaxf(m, 0.0f));          // dmin
    }
    __syncthreads();

    float kk2[2], c02[2];
#pragma unroll
    for (int xt = 0; xt < 2; ++xt) {
        float dm = dmf[xt * 16 + lrow];
        kk2[xt] = LOG2E / (SIGMA * (dm + EPS_MIN));
        c02[xt] = dm * kk2[xt];
    }

    // ---------------- sweep 2: exp-sum ----------------
    float s2[2] = {0.0f, 0.0f};
    {
        Frag fa = LDT(0), fb = LDT(1);
        for (int t = 0; t < NT; t += 2) {
            Frag fc = {}, fd = {};
            if (t + 2 < NT) fc = LDT(t + 2);
            if (t + 3 < NT) fd = LDT(t + 3);
#pragma unroll
            for (int xt = 0; xt < 2; ++xt) {
                floatx4 acc = {2.0f, 2.0f, 2.0f, 2.0f};
                acc = __builtin_amdgcn_mfma_f32_16x16x32_bf16(fa.a0, xf0[xt], acc, 0, 0, 0);
                acc = __builtin_amdgcn_mfma_f32_16x16x32_bf16(fa.a1, xf1[xt], acc, 0, 0, 0);
#pragma unroll
                for (int r = 0; r < 4; ++r) {
                    float d = __builtin_amdgcn_sqrtf(acc[r]);   // d^2 >= ~1.1 here
                    s2[xt] += __builtin_amdgcn_exp2f(fmaf(-kk2[xt], d, c02[xt]));
                }
            }
#pragma unroll
            for (int xt = 0; xt < 2; ++xt) {
                floatx4 acc = {2.0f, 2.0f, 2.0f, 2.0f};
                acc = __builtin_amdgcn_mfma_f32_16x16x32_bf16(fb.a0, xf0[xt], acc, 0, 0, 0);
                acc = __builtin_amdgcn_mfma_f32_16x16x32_bf16(fb.a1, xf1[xt], acc, 0, 0, 0);
#pragma unroll
                for (int r = 0; r < 4; ++r) {
                    float d = __builtin_amdgcn_sqrtf(acc[r]);
                    s2[xt] += __builtin_amdgcn_exp2f(fmaf(-kk2[xt], d, c02[xt]));
                }
            }
            fa = fc; fb = fd;
        }
    }
#undef LDT

#pragma unroll
    for (int off = 16; off < 64; off <<= 1) {
        s2[0] += __shfl_xor(s2[0], off);
        s2[1] += __shfl_xor(s2[1], off);
    }
    if (kgrp == 0) { red[wid][lrow] = s2[0]; red[wid][16 + lrow] = s2[1]; }
    __syncthreads();

    // Block partial of sum(1/S + eps) -> one atomicAdd.
    if (tid < 64) {
        float acc = 0.0f;
        if (tid < XR) {
            float Ssum = red[0][tid];
#pragma unroll
            for (int w = 1; w < NW; ++w) Ssum += red[w][tid];
            acc = __builtin_amdgcn_rcpf(Ssum) + EPS_MIN;
        }
#pragma unroll
        for (int off = 16; off > 0; off >>= 1) acc += __shfl_down(acc, off);
        if (tid == 0) atomicAdd(total, acc);
    }
}

// ---------------------------------------------------------------------------
__global__ void final_kernel(const float* __restrict__ total,
                             float* __restrict__ out) {
    out[0] = -logf(total[0] / (float)ROWS);
}

// ---------------------------------------------------------------------------
extern "C" void kernel_launch(void* const* d_in, const int* in_sizes, int n_in,
                              void* d_out, int out_size, void* d_ws, size_t ws_size,
                              hipStream_t stream) {
    const float* x = (const float*)d_in[0];
    const float* y = (const float*)d_in[1];
    float* out = (float*)d_out;

    char* ws = (char*)d_ws;
    size_t nrm_bytes = (size_t)ROWS * C_ * sizeof(ushort);   // 2 MB each
    ushort* xn    = (ushort*)(ws);
    ushort* yn    = (ushort*)(ws + nrm_bytes);
    float*  total = (float*)(ws + 2 * nrm_bytes);

    hipLaunchKernelGGL(nrm_kernel, dim3(2 * ROWS / 256), dim3(256), 0, stream,
                       x, y, xn, yn, total);
    hipLaunchKernelGGL(main_kernel, dim3(ROWS / XR), dim3(512), 0, stream,
                       xn, yn, total);
    hipLaunchKernelGGL(final_kernel, dim3(1), dim3(1), 0, stream, total, out);
}

// Round 11
// 93.286 us; speedup vs baseline: 1.3655x; 1.3655x over previous
//
#include <hip/hip_runtime.h>
#include <math.h>

// Problem constants (fixed by the reference): x,y are [4, 64, 64, 64] fp32.
constexpr int B_   = 4;
constexpr int C_   = 64;
constexpr int HW   = 4096;         // N = 64*64
constexpr int ROWS = B_ * HW;      // 16384

constexpr float SIGMA    = 0.1f;
constexpr float EPS_MIN  = 1e-5f;
constexpr float EPS_NORM = 1e-12f;
constexpr float LOG2E    = 1.44269504088896340736f;

// Fused-kernel geometry (R8 structure, bigger x-tile): block owns XR=64
// x-rows x ALL 4096 y of one batch (dmin block-local -> one atomicAdd per
// block).  16 waves (1024 thr) split y 16-ways; each wave stages its y
// through PRIVATE LDS dbuf (no __syncthreads in sweeps).  xt=4 -> each
// staged ya pair feeds 8 MFMAs (2x R8): LDS pipe per element halves.
// Grid 256 = 1 block/CU, 16 waves = 4 waves/SIMD.
constexpr int XR  = 64;            // x-rows per block (4 MFMA col-tiles)
constexpr int NW  = 16;            // waves per block
constexpr int YW  = HW / NW;       // 256 y-rows per wave
constexpr int SRW = 32;            // y-rows per wave-private stage (4 KB)
constexpr int NSW = YW / SRW;      // 8 stages per sweep

using short8  = __attribute__((ext_vector_type(8))) short;   // 8 bf16
using floatx4 = __attribute__((ext_vector_type(4))) float;

__device__ inline ushort f2bf(float f) {           // RNE float->bf16
    unsigned u = __float_as_uint(f);
    unsigned r = u + 0x7FFFu + ((u >> 16) & 1u);
    return (ushort)(r >> 16);
}

// ---------------------------------------------------------------------------
// Normalize along C, write bf16 [B][N][C] point-major.
// TRICK (verified R9): xn pre-scaled by -2 (exact in bf16) so MFMA with
// C-init=2 produces d^2 = 2 - 2*dot directly.  yn is the plain unit vector.
__global__ __launch_bounds__(256) void nrm_kernel(const float* __restrict__ x,
                                                  const float* __restrict__ y,
                                                  ushort* __restrict__ xn,
                                                  ushort* __restrict__ yn,
                                                  float* __restrict__ total) {
    int p = blockIdx.x * 256 + threadIdx.x;        // 0 .. 2*ROWS-1
    if (p == 0) *total = 0.0f;
    const float* src; ushort* dst; int q; float sgn;
    if (p < ROWS) { src = x; dst = xn; q = p; sgn = -2.0f; }
    else          { src = y; dst = yn; q = p - ROWS; sgn = 1.0f; }
    int b = q >> 12;
    int n = q & (HW - 1);
    const float* base = src + ((size_t)b * C_) * HW + n;  // coalesced over n
    float v[C_];
    float ss = 0.0f;
#pragma unroll
    for (int c = 0; c < C_; ++c) {
        v[c] = base[(size_t)c * HW];
        ss = fmaf(v[c], v[c], ss);
    }
    float scale = sgn / fmaxf(sqrtf(ss), EPS_NORM);
    short8* o = (short8*)(dst + (size_t)q * C_);
#pragma unroll
    for (int c8 = 0; c8 < C_ / 8; ++c8) {
        short8 pk;
#pragma unroll
        for (int j = 0; j < 8; ++j) pk[j] = (short)f2bf(v[c8 * 8 + j] * scale);
        o[c8] = pk;
    }
}

// ---------------------------------------------------------------------------
// Fused kernel. Swapped-operand MFMA (A=y, B=-2x, C=2): D = d^2 directly;
// D col = x point (lane&15), D row = y point.  Per-x-row reduction over y
// is in-register; cross-kgrp combine is 2 shfls per sweep.
// Sweep 1: min d^2 -> dmin (block-local LDS reduce across 16 waves).
// Sweep 2: S_row = sum_m exp2((dmin-d)*kk2), kk2 = log2e/(sigma*(dmin+eps));
//          then one atomicAdd per block of sum_rows(1/S + eps).
__global__ __launch_bounds__(1024, 4) void main_kernel(const ushort* __restrict__ xn,
                                                       const ushort* __restrict__ yn,
                                                       float* __restrict__ total) {
    __shared__ short8 stg[NW][2][SRW * 8];         // wave-private dbuf, 128 KB
    __shared__ float  red[NW][XR];                 // 4 KB
    __shared__ float  dmf[XR];

    const int tid  = threadIdx.x;
    const int wid  = tid >> 6;                     // 0..15
    const int lane = tid & 63;
    const int lrow = lane & 15;                    // x-col within tile
    const int kgrp = lane >> 4;                    // k-group 0..3

    const int blk   = blockIdx.x;
    const int b     = blk >> 6;                    // 64 blocks per batch
    const int nbase = (blk & 63) * XR;

    // x B-fragments (pre-scaled by -2): 4 tiles x (k 0..31, k 32..63).
    const ushort* xb = xn + (size_t)(b * HW + nbase) * C_;
    short8 xf0[4], xf1[4];
#pragma unroll
    for (int xt = 0; xt < 4; ++xt) {
        xf0[xt] = *(const short8*)(xb + (xt * 16 + lrow) * C_ + kgrp * 8);
        xf1[xt] = *(const short8*)(xb + (xt * 16 + lrow) * C_ + 32 + kgrp * 8);
    }

    // This wave's y-sixteenth, in 16B units (8 units per y-row).
    const short8* yq = (const short8*)(yn + (size_t)(b * HW + wid * YW) * C_);
    // Staging: lane handles units g*64+lane (g=0..3) per stage. Swizzled
    // write slot: row = g*8+(lane>>3), slot = lane&7; (row&7) == lane>>3.
    const int wbase = (lane >> 3) * 8 + ((lane & 7) ^ (lane >> 3));

    short8 v[4];
    float m2[4] = {INFINITY, INFINITY, INFINITY, INFINITY};  // sweep-1 min d^2

    // ---------------- sweep 1: min d^2 ----------------
#pragma unroll
    for (int g = 0; g < 4; ++g) v[g] = yq[g * 64 + lane];
#pragma unroll
    for (int g = 0; g < 4; ++g) stg[wid][0][g * 64 + wbase] = v[g];

    for (int s = 0; s < NSW; ++s) {
        int cur = s & 1;
        if (s + 1 < NSW) {                         // issue-early (T14)
#pragma unroll
            for (int g = 0; g < 4; ++g) v[g] = yq[(s + 1) * 256 + g * 64 + lane];
        }
#pragma unroll
        for (int yt = 0; yt < 2; ++yt) {
            int p = yt * 16 + lrow, q = p & 7;
            short8 ya0 = stg[wid][cur][p * 8 + (kgrp ^ q)];         // k 0..31
            short8 ya1 = stg[wid][cur][p * 8 + ((kgrp + 4) ^ q)];   // k 32..63
#pragma unroll
            for (int xt = 0; xt < 4; ++xt) {
                floatx4 acc = {2.0f, 2.0f, 2.0f, 2.0f};
                acc = __builtin_amdgcn_mfma_f32_16x16x32_bf16(ya0, xf0[xt], acc, 0, 0, 0);
                acc = __builtin_amdgcn_mfma_f32_16x16x32_bf16(ya1, xf1[xt], acc, 0, 0, 0);
                m2[xt] = fminf(m2[xt],
                         fminf(fminf(acc[0], acc[1]), fminf(acc[2], acc[3])));
            }
        }
        if (s + 1 < NSW) {                         // write-late (T14)
#pragma unroll
            for (int g = 0; g < 4; ++g) stg[wid][cur ^ 1][g * 64 + wbase] = v[g];
        }
    }

    // Combine the 4 k-groups, then the 16 waves (disjoint y-subsets).
#pragma unroll
    for (int off = 16; off < 64; off <<= 1)
#pragma unroll
        for (int xt = 0; xt < 4; ++xt)
            m2[xt] = fminf(m2[xt], __shfl_xor(m2[xt], off));
    if (kgrp == 0)
#pragma unroll
        for (int xt = 0; xt < 4; ++xt) red[wid][xt * 16 + lrow] = m2[xt];
    __syncthreads();
    if (tid < XR) {
        float m = red[0][tid];
#pragma unroll
        for (int w = 1; w < NW; ++w) m = fminf(m, red[w][tid]);
        dmf[tid] = sqrtf(fmaxf(m, 0.0f));          // dmin
    }
    __syncthreads();

    float kk2[4], c02[4];
#pragma unroll
    for (int xt = 0; xt < 4; ++xt) {
        float dm = dmf[xt * 16 + lrow];
        kk2[xt] = LOG2E / (SIGMA * (dm + EPS_MIN));
        c02[xt] = dm * kk2[xt];
    }

    // ---------------- sweep 2: exp-sum ----------------
    float s2[4] = {0.0f, 0.0f, 0.0f, 0.0f};
#pragma unroll
    for (int g = 0; g < 4; ++g) v[g] = yq[g * 64 + lane];
#pragma unroll
    for (int g = 0; g < 4; ++g) stg[wid][0][g * 64 + wbase] = v[g];

    for (int s = 0; s < NSW; ++s) {
        int cur = s & 1;
        if (s + 1 < NSW) {
#pragma unroll
            for (int g = 0; g < 4; ++g) v[g] = yq[(s + 1) * 256 + g * 64 + lane];
        }
#pragma unroll
        for (int yt = 0; yt < 2; ++yt) {
            int p = yt * 16 + lrow, q = p & 7;
            short8 ya0 = stg[wid][cur][p * 8 + (kgrp ^ q)];
            short8 ya1 = stg[wid][cur][p * 8 + ((kgrp + 4) ^ q)];
#pragma unroll
            for (int xt = 0; xt < 4; ++xt) {
                floatx4 acc = {2.0f, 2.0f, 2.0f, 2.0f};
                acc = __builtin_amdgcn_mfma_f32_16x16x32_bf16(ya0, xf0[xt], acc, 0, 0, 0);
                acc = __builtin_amdgcn_mfma_f32_16x16x32_bf16(ya1, xf1[xt], acc, 0, 0, 0);
#pragma unroll
                for (int r = 0; r < 4; ++r) {
                    float d = __builtin_amdgcn_sqrtf(acc[r]);   // d^2 >= ~1.1
                    s2[xt] += __builtin_amdgcn_exp2f(fmaf(-kk2[xt], d, c02[xt]));
                }
            }
        }
        if (s + 1 < NSW) {
#pragma unroll
            for (int g = 0; g < 4; ++g) stg[wid][cur ^ 1][g * 64 + wbase] = v[g];
        }
    }

#pragma unroll
    for (int off = 16; off < 64; off <<= 1)
#pragma unroll
        for (int xt = 0; xt < 4; ++xt)
            s2[xt] += __shfl_xor(s2[xt], off);
    if (kgrp == 0)
#pragma unroll
        for (int xt = 0; xt < 4; ++xt) red[wid][xt * 16 + lrow] = s2[xt];
    __syncthreads();

    // Block partial of sum(1/S + eps) -> one atomicAdd.
    if (tid < 64) {
        float Ssum = red[0][tid];
#pragma unroll
        for (int w = 1; w < NW; ++w) Ssum += red[w][tid];
        float acc = __builtin_amdgcn_rcpf(Ssum) + EPS_MIN;
#pragma unroll
        for (int off = 32; off > 0; off >>= 1) acc += __shfl_down(acc, off);
        if (tid == 0) atomicAdd(total, acc);
    }
}

// ---------------------------------------------------------------------------
__global__ void final_kernel(const float* __restrict__ total,
                             float* __restrict__ out) {
    out[0] = -logf(total[0] / (float)ROWS);
}

// ---------------------------------------------------------------------------
extern "C" void kernel_launch(void* const* d_in, const int* in_sizes, int n_in,
                              void* d_out, int out_size, void* d_ws, size_t ws_size,
                              hipStream_t stream) {
    const float* x = (const float*)d_in[0];
    const float* y = (const float*)d_in[1];
    float* out = (float*)d_out;

    char* ws = (char*)d_ws;
    size_t nrm_bytes = (size_t)ROWS * C_ * sizeof(ushort);   // 2 MB each
    ushort* xn    = (ushort*)(ws);
    ushort* yn    = (ushort*)(ws + nrm_bytes);
    float*  total = (float*)(ws + 2 * nrm_bytes);

    hipLaunchKernelGGL(nrm_kernel, dim3(2 * ROWS / 256), dim3(256), 0, stream,
                       x, y, xn, yn, total);
    hipLaunchKernelGGL(main_kernel, dim3(ROWS / XR), dim3(1024), 0, stream,
                       xn, yn, total);
    hipLaunchKernelGGL(final_kernel, dim3(1), dim3(1), 0, stream, total, out);
}